// Round 1
// baseline (389.332 us; speedup 1.0000x reference)
//
#include <hip/hip_runtime.h>
#include <hip/hip_bf16.h>

typedef __attribute__((ext_vector_type(8))) short bf16x8;
typedef __attribute__((ext_vector_type(4))) float f32x4;

union BF8 { bf16x8 v; unsigned short u[8]; };
union F4  { f32x4 v; float f[4]; };

__device__ __forceinline__ unsigned short f2bf(float f) {
  union { float f; unsigned u; } a; a.f = f;
  return (unsigned short)((a.u + 0x7fffu + ((a.u >> 16) & 1u)) >> 16);
}
__device__ __forceinline__ float bf2f(unsigned short u) {
  union { unsigned u; float f; } a; a.u = ((unsigned)u) << 16;
  return a.f;
}

// Block: 256 threads (4 waves), 8 batch rows => 64 chunk-rows (M=64).
// LDS: pe[8][132] f32 | xcA: swizzled bf16 [64][128] | uni: QKV bf16 [64][264] then h f32 [64][132]
__global__ __launch_bounds__(256, 2)
void wlmha_fused(const float* __restrict__ x,
                 const float* __restrict__ Wq,
                 const float* __restrict__ Wk,
                 const float* __restrict__ Wv,
                 const float* __restrict__ Wo,
                 const float* __restrict__ gamma,
                 const float* __restrict__ beta,
                 const float* __restrict__ relb,
                 float* __restrict__ y_out,
                 float* __restrict__ attn_out)
{
  const int t    = threadIdx.x;
  const int lane = t & 63;
  const int w    = t >> 6;        // wave 0..3
  const int lrow = lane & 15;
  const int kq   = lane >> 4;     // 0..3 (k-subgroup)
  const long b0  = (long)blockIdx.x * 8;

  __shared__ float pe[8][132];
  __shared__ float s_gam[128];
  __shared__ float s_bet[128];
  __shared__ float s_rel[2][16];
  __shared__ float s_stats[64][2];
  __shared__ unsigned short xcA[64 * 128];
  __shared__ __align__(16) char uni[64 * 528];

  unsigned short* qkv = (unsigned short*)uni;  // [64][264] bf16
  float* hbuf = (float*)uni;                   // [64][132] f32

  // ---------------- Phase 0: global loads + PE + small params ----------------
  f32x4 xg[4][2];
  {
    const float* xb = x + b0 * 1024;
#pragma unroll
    for (int i = 0; i < 4; ++i) {
      const float* p = xb + (t + 256 * i) * 8;
      xg[i][0] = *(const f32x4*)p;
      xg[i][1] = *(const f32x4*)(p + 4);
    }
  }

  bf16x8 wqkv[4][4];  // [nb][ks] B-fragments, wave's 64-col slice of [Q|K|V]
#pragma unroll
  for (int nb = 0; nb < 4; ++nb) {
    const int n = w * 64 + nb * 16 + lrow;
    const float* src = (n < 64) ? (Wq + n * 128)
                    : (n < 128) ? (Wk + (n - 64) * 128)
                                : (Wv + (n - 128) * 128);
#pragma unroll
    for (int ks = 0; ks < 4; ++ks) {
      const float* p = src + ks * 32 + kq * 8;
      F4 a, b; a.v = *(const f32x4*)p; b.v = *(const f32x4*)(p + 4);
      BF8 fr;
#pragma unroll
      for (int j = 0; j < 4; ++j) { fr.u[j] = f2bf(a.f[j]); fr.u[4 + j] = f2bf(b.f[j]); }
      wqkv[nb][ks] = fr.v;
    }
  }

  bf16x8 wo[2][4];    // wave's 32-col slice of Wo
#pragma unroll
  for (int nb = 0; nb < 2; ++nb) {
    const int n = w * 32 + nb * 16 + lrow;
    const float* src = Wo + n * 128;
#pragma unroll
    for (int ks = 0; ks < 4; ++ks) {
      const float* p = src + ks * 32 + kq * 8;
      F4 a, b; a.v = *(const f32x4*)p; b.v = *(const f32x4*)(p + 4);
      BF8 fr;
#pragma unroll
      for (int j = 0; j < 4; ++j) { fr.u[j] = f2bf(a.f[j]); fr.u[4 + j] = f2bf(b.f[j]); }
      wo[nb][ks] = fr.v;
    }
  }

  for (int e = t; e < 512; e += 256) {
    const int c = e >> 6, i = e & 63;
    const float div = expf(-0.14391156831212727f * (float)i);  // 10000^(-i/64)
    const float ang = (float)c * div;
    float s, co;
    sincosf(ang, &s, &co);
    pe[c][2 * i]     = s;
    pe[c][2 * i + 1] = co;
  }
  if (t < 128) { s_gam[t] = gamma[t]; s_bet[t] = beta[t]; }
  if (t < 30)  { s_rel[t / 15][t % 15] = relb[t]; }
  __syncthreads();

  // ---------------- Phase 1: xcA = bf16(x + pe), XOR-swizzled ----------------
#pragma unroll
  for (int i = 0; i < 4; ++i) {
    const int g = t + 256 * i;      // granule of 8 floats; flat elem = g*8
    const int m = g >> 4;           // chunk-row 0..63
    const int c = (g & 15) * 8;     // col 0..120
    const float* per = &pe[m & 7][c];
    BF8 fr;
#pragma unroll
    for (int j = 0; j < 4; ++j) {
      fr.u[j]     = f2bf(xg[i][0][j] + per[j]);
      fr.u[4 + j] = f2bf(xg[i][1][j] + per[4 + j]);
    }
    const int byte = m * 256 + ((c * 2) ^ ((m & 7) << 4));
    *(bf16x8*)((char*)xcA + byte) = fr.v;
  }
  __syncthreads();

  // ---------------- Phase 2: QKV = xc @ [Wq|Wk|Wv]^T via MFMA ----------------
#pragma unroll
  for (int mt = 0; mt < 4; ++mt) {
    const int am = mt * 16 + lrow;
    bf16x8 afr[4];
#pragma unroll
    for (int ks = 0; ks < 4; ++ks) {
      const int byte = am * 256 + ((ks * 64 + kq * 16) ^ ((am & 7) << 4));
      afr[ks] = *(const bf16x8*)((const char*)xcA + byte);
    }
#pragma unroll
    for (int nb = 0; nb < 4; ++nb) {
      f32x4 acc = {0.f, 0.f, 0.f, 0.f};
#pragma unroll
      for (int ks = 0; ks < 4; ++ks)
        acc = __builtin_amdgcn_mfma_f32_16x16x32_bf16(afr[ks], wqkv[nb][ks], acc, 0, 0, 0);
      const int n  = w * 64 + nb * 16 + lrow;       // 0..255
      const int rb = mt * 16 + kq * 4;
#pragma unroll
      for (int j = 0; j < 4; ++j)
        qkv[(rb + j) * 264 + n] = f2bf(acc[j]);
    }
  }
  __syncthreads();

  // ---------------- Phase 3: attention (2 threads per (r,h,qc)) ----------------
  {
    const int trip = t >> 1;
    const int vh = t & 1;           // v-half 0/1
    const int qc = trip & 7;
    const int h  = (trip >> 3) & 1;
    const int r  = trip >> 4;       // 0..7
    const int mrow = r * 8 + qc;

    float q[32];
    {
      const unsigned short* Qp = qkv + mrow * 264 + h * 32;
#pragma unroll
      for (int gq = 0; gq < 4; ++gq) {
        BF8 fr; fr.v = *(const bf16x8*)(Qp + gq * 8);
#pragma unroll
        for (int j = 0; j < 8; ++j) q[gq * 8 + j] = bf2f(fr.u[j]);
      }
    }
    float s[8];
#pragma unroll
    for (int mc = 0; mc < 8; ++mc) {
      const unsigned short* Kp = qkv + (r * 8 + mc) * 264 + 64 + h * 32;
      float acc = 0.f;
#pragma unroll
      for (int gq = 0; gq < 4; ++gq) {
        BF8 fr; fr.v = *(const bf16x8*)(Kp + gq * 8);
#pragma unroll
        for (int j = 0; j < 8; ++j) acc += q[gq * 8 + j] * bf2f(fr.u[j]);
      }
      s[mc] = acc * 0.17677669529663687f + s_rel[h][mc - qc + 7];
    }
    float mx = s[0];
#pragma unroll
    for (int mc = 1; mc < 8; ++mc) mx = fmaxf(mx, s[mc]);
    float p[8], sum = 0.f;
#pragma unroll
    for (int mc = 0; mc < 8; ++mc) { p[mc] = __expf(s[mc] - mx); sum += p[mc]; }
    const float inv = 1.0f / sum;
#pragma unroll
    for (int mc = 0; mc < 8; ++mc) p[mc] *= inv;

    if (vh == 0) {
      float* ap = attn_out + ((b0 + r) * 2 + h) * 64 + qc * 8;
      f32x4 v0 = {p[0], p[1], p[2], p[3]};
      f32x4 v1 = {p[4], p[5], p[6], p[7]};
      *(f32x4*)ap = v0;
      *(f32x4*)(ap + 4) = v1;
    }

    float ctx[32];
#pragma unroll
    for (int v = 0; v < 32; ++v) ctx[v] = 0.f;
#pragma unroll
    for (int mc = 0; mc < 8; ++mc) {
      const unsigned short* Vp = qkv + (r * 8 + mc) * 264 + 128 + h * 64 + vh * 32;
      const float pm = p[mc];
#pragma unroll
      for (int gq = 0; gq < 4; ++gq) {
        BF8 fr; fr.v = *(const bf16x8*)(Vp + gq * 8);
#pragma unroll
        for (int j = 0; j < 8; ++j) ctx[gq * 8 + j] += pm * bf2f(fr.u[j]);
      }
    }
    // ctx -> swizzled A-buffer (reuses xcA; phase-2 readers are past the barrier)
#pragma unroll
    for (int gq = 0; gq < 4; ++gq) {
      BF8 fr;
#pragma unroll
      for (int j = 0; j < 8; ++j) fr.u[j] = f2bf(ctx[gq * 8 + j]);
      const int bytecol = (h * 64 + vh * 32 + gq * 8) * 2;
      const int byte = mrow * 256 + (bytecol ^ ((mrow & 7) << 4));
      *(bf16x8*)((char*)xcA + byte) = fr.v;
    }
  }
  __syncthreads();

  // ---------------- Phase 4: out = ctx @ Wo^T via MFMA -> hbuf (aliases qkv) ----------------
#pragma unroll
  for (int mt = 0; mt < 4; ++mt) {
    const int am = mt * 16 + lrow;
    bf16x8 afr[4];
#pragma unroll
    for (int ks = 0; ks < 4; ++ks) {
      const int byte = am * 256 + ((ks * 64 + kq * 16) ^ ((am & 7) << 4));
      afr[ks] = *(const bf16x8*)((const char*)xcA + byte);
    }
#pragma unroll
    for (int nb = 0; nb < 2; ++nb) {
      f32x4 acc = {0.f, 0.f, 0.f, 0.f};
#pragma unroll
      for (int ks = 0; ks < 4; ++ks)
        acc = __builtin_amdgcn_mfma_f32_16x16x32_bf16(afr[ks], wo[nb][ks], acc, 0, 0, 0);
      const int n  = w * 32 + nb * 16 + lrow;   // 0..127
      const int rb = mt * 16 + kq * 4;
#pragma unroll
      for (int j = 0; j < 4; ++j)
        hbuf[(rb + j) * 132 + n] = acc[j];
    }
  }
  __syncthreads();

  // ---------------- Phase 5: h += x + pe ----------------
#pragma unroll
  for (int i = 0; i < 4; ++i) {
    const int g = t + 256 * i;
    const int m = g >> 4;
    const int c = (g & 15) * 8;
    float* hp = hbuf + m * 132 + c;
    const float* per = &pe[m & 7][c];
    f32x4 h0 = *(f32x4*)hp;
    f32x4 h1 = *(f32x4*)(hp + 4);
#pragma unroll
    for (int j = 0; j < 4; ++j) {
      h0[j] += xg[i][0][j] + per[j];
      h1[j] += xg[i][1][j] + per[4 + j];
    }
    *(f32x4*)hp = h0;
    *(f32x4*)(hp + 4) = h1;
  }
  __syncthreads();

  // ---------------- Phase 6: LN stats (4 lanes per row) ----------------
  {
    const int m = t >> 2, qd = t & 3;
    const float* hp = hbuf + m * 132 + qd * 32;
    float sum = 0.f, sq = 0.f;
#pragma unroll
    for (int jj = 0; jj < 8; ++jj) {
      f32x4 v = *(const f32x4*)(hp + jj * 4);
#pragma unroll
      for (int j = 0; j < 4; ++j) { sum += v[j]; sq += v[j] * v[j]; }
    }
    sum += __shfl_xor(sum, 1); sq += __shfl_xor(sq, 1);
    sum += __shfl_xor(sum, 2); sq += __shfl_xor(sq, 2);
    if (qd == 0) {
      const float mu  = sum * (1.f / 128.f);
      const float var = sq * (1.f / 128.f) - mu * mu;
      s_stats[m][0] = mu;
      s_stats[m][1] = rsqrtf(var + 1e-5f);
    }
  }
  __syncthreads();

  // ---------------- Phase 7: y = LN(h)*gamma + beta, coalesced stores ----------------
  {
    float* yb = y_out + b0 * 1024;
#pragma unroll
    for (int i = 0; i < 4; ++i) {
      const int g = t + 256 * i;
      const int m = g >> 4;
      const int c = (g & 15) * 8;
      const float mu = s_stats[m][0], rs = s_stats[m][1];
      const float* hp = hbuf + m * 132 + c;
      f32x4 o0, o1;
#pragma unroll
      for (int j = 0; j < 4; ++j) {
        o0[j] = (hp[j]     - mu) * rs * s_gam[c + j]     + s_bet[c + j];
        o1[j] = (hp[4 + j] - mu) * rs * s_gam[c + 4 + j] + s_bet[c + 4 + j];
      }
      float* yp = yb + g * 8;
      *(f32x4*)yp = o0;
      *(f32x4*)(yp + 4) = o1;
    }
  }
}

extern "C" void kernel_launch(void* const* d_in, const int* in_sizes, int n_in,
                              void* d_out, int out_size, void* d_ws, size_t ws_size,
                              hipStream_t stream) {
  const float* x     = (const float*)d_in[0];
  const float* Wq    = (const float*)d_in[1];
  const float* Wk    = (const float*)d_in[2];
  const float* Wv    = (const float*)d_in[3];
  const float* Wo    = (const float*)d_in[4];
  const float* gam   = (const float*)d_in[5];
  const float* bet   = (const float*)d_in[6];
  const float* relb  = (const float*)d_in[7];
  float* y    = (float*)d_out;
  float* attn = y + (size_t)65536 * 1024;   // outputs concatenated: y then attn
  hipLaunchKernelGGL(wlmha_fused, dim3(8192), dim3(256), 0, stream,
                     x, Wq, Wk, Wv, Wo, gam, bet, relb, y, attn);
}

// Round 2
// 172.154 us; speedup vs baseline: 2.2615x; 2.2615x over previous
//
#include <hip/hip_runtime.h>

typedef __attribute__((ext_vector_type(8))) short bf16x8;
typedef __attribute__((ext_vector_type(4))) float f32x4;
typedef __attribute__((ext_vector_type(2))) unsigned int u32x2;

__device__ __forceinline__ unsigned short f2bf(float f) {
  union { float f; unsigned u; } a; a.f = f;
  return (unsigned short)((a.u + 0x7fffu + ((a.u >> 16) & 1u)) >> 16);
}
__device__ __forceinline__ unsigned pk2bf(float lo, float hi) {
  return (unsigned)f2bf(lo) | ((unsigned)f2bf(hi) << 16);
}

union UB8 { bf16x8 v; unsigned d[4]; };

// ---------------- pre-kernel: weights -> bf16 once ----------------
// ws layout: [0..8191] Wq, [8192..16383] Wk, [16384..32767] Wv  (= combined [256][128])
//            [32768..49151] Wo [128][128]
__global__ void wconv_kernel(const float* __restrict__ Wq, const float* __restrict__ Wk,
                             const float* __restrict__ Wv, const float* __restrict__ Wo,
                             unsigned short* __restrict__ ws) {
  int i = blockIdx.x * 256 + threadIdx.x;
  float v;
  if (i < 8192) v = Wq[i];
  else if (i < 16384) v = Wk[i - 8192];
  else if (i < 32768) v = Wv[i - 16384];
  else v = Wo[i - 32768];
  ws[i] = f2bf(v);
}

// ---------------- fused kernel ----------------
// Block: 256 threads (4 waves), 8 batch rows = 64 chunk-rows.
// LDS (49280 B -> 3 blocks/CU):
//   [0..32767]     union: pe f32[8][132] (ph0-1) | qk bf16[64 rows x 256B] swz + Vt bf16[128 vrows x 128B] swz (ph2-3) | hbuf f32[64 rows x 512B] swz (ph4-5)
//   [32768..49151] xcA bf16[64 rows x 256B] swz  (xc for QKV; then ctx)
//   [49152..49279] s_rel [2][16]
// All bf16 tiles use byte(e) = (2e) ^ ((row&7)<<4); hbuf uses (4e) ^ ((row&7)<<4).
__global__ __launch_bounds__(256, 3)
void wlmha_kernel(const float* __restrict__ x,
                  const unsigned short* __restrict__ wA,   // [256][128] Q|K|V
                  const unsigned short* __restrict__ wOb,  // [128][128] Wo
                  const float* __restrict__ gamma,
                  const float* __restrict__ beta,
                  const float* __restrict__ relb,
                  float* __restrict__ y_out,
                  float* __restrict__ attn_out)
{
  const int t = threadIdx.x;
  const int l = t & 63;
  const int w = t >> 6;
  const long b0 = (long)blockIdx.x * 8;

  __shared__ __align__(16) char smem[49280];
  float* peS  = (float*)smem;
  char*  qkS  = smem;
  char*  vtS  = smem + 16384;
  char*  hbS  = smem;
  char*  xcS  = smem + 32768;
  float* s_rel = (float*)(smem + 49152);

  // ---------------- Phase 0: x loads, weight frags, PE, rel bias ----------------
  f32x4 xr[4][2];
  {
    const float* xb = x + b0 * 1024;
#pragma unroll
    for (int i = 0; i < 4; ++i) {
      const float* p = xb + (t + 256 * i) * 8;
      xr[i][0] = *(const f32x4*)p;
      xr[i][1] = *(const f32x4*)(p + 4);
    }
  }
  // QKV weight frags: wave's 64-col slice of combined [256][128].
  // waves 0,1: used as A (W rows);  waves 2,3: used as B (Wv rows). Same load pattern.
  bf16x8 wf[4][4];
#pragma unroll
  for (int nb = 0; nb < 4; ++nb) {
    const unsigned short* src = wA + (w * 64 + nb * 16 + (l & 15)) * 128 + (l >> 4) * 8;
#pragma unroll
    for (int ks = 0; ks < 4; ++ks) wf[nb][ks] = *(const bf16x8*)(src + ks * 32);
  }
  for (int e = t; e < 512; e += 256) {
    const int c = e >> 6, i = e & 63;
    const float div = expf(-0.14391156831212727f * (float)i);  // 10000^(-2i/128)
    float s, co;
    sincosf((float)c * div, &s, &co);
    peS[c * 132 + 2 * i]     = s;
    peS[c * 132 + 2 * i + 1] = co;
  }
  if (t < 30) s_rel[(t / 15) * 16 + (t % 15)] = relb[t];
  __syncthreads();

  // ---------------- Phase 1: xc = x + pe (kept in regs); bf16 -> xcA swz ----------------
#pragma unroll
  for (int i = 0; i < 4; ++i) {
    const int g = t + 256 * i;
    const int m = g >> 4;
    const int c = (g & 15) * 8;
    const float* per = peS + (m & 7) * 132 + c;
    UB8 fr;
#pragma unroll
    for (int j = 0; j < 4; ++j) { xr[i][0][j] += per[j]; xr[i][1][j] += per[4 + j]; }
    fr.d[0] = pk2bf(xr[i][0][0], xr[i][0][1]);
    fr.d[1] = pk2bf(xr[i][0][2], xr[i][0][3]);
    fr.d[2] = pk2bf(xr[i][1][0], xr[i][1][1]);
    fr.d[3] = pk2bf(xr[i][1][2], xr[i][1][3]);
    *(bf16x8*)(xcS + m * 256 + ((c * 2) ^ ((m & 7) << 4))) = fr.v;
  }
  __syncthreads();

  // ---------------- Phase 2: QKV projection via MFMA ----------------
  // waves 0,1: D[n,m] = sum_k W[n,k] xc[m,k]  (A=W, B=xc) -> packed rows of qk
  // waves 2,3: D[m,n] = sum_k xc[m,k] Wv[n,k] (A=xc, B=W) -> packed cols into Vt (transposed V)
#pragma unroll
  for (int mt = 0; mt < 4; ++mt) {
    bf16x8 xf[4];
    const int row = mt * 16 + (l & 15);
#pragma unroll
    for (int ks = 0; ks < 4; ++ks)
      xf[ks] = *(const bf16x8*)(xcS + row * 256 + ((ks * 64 + (l >> 4) * 16) ^ ((row & 7) << 4)));
    if (w < 2) {
#pragma unroll
      for (int nb = 0; nb < 4; ++nb) {
        f32x4 acc = {0.f, 0.f, 0.f, 0.f};
#pragma unroll
        for (int ks = 0; ks < 4; ++ks)
          acc = __builtin_amdgcn_mfma_f32_16x16x32_bf16(wf[nb][ks], xf[ks], acc, 0, 0, 0);
        // lane holds n = w*64+nb*16+(l>>4)*4+j for row m
        u32x2 pk; pk.x = pk2bf(acc[0], acc[1]); pk.y = pk2bf(acc[2], acc[3]);
        const int colb = (w * 128 + nb * 32 + (l >> 4) * 8) ^ ((row & 7) << 4);
        *(u32x2*)(qkS + row * 256 + colb) = pk;
      }
    } else {
#pragma unroll
      for (int nb = 0; nb < 4; ++nb) {
        f32x4 acc = {0.f, 0.f, 0.f, 0.f};
#pragma unroll
        for (int ks = 0; ks < 4; ++ks)
          acc = __builtin_amdgcn_mfma_f32_16x16x32_bf16(xf[ks], wf[nb][ks], acc, 0, 0, 0);
        // lane: v-feature nv = (w-2)*64+nb*16+(l&15), key rows rb..rb+3
        const int nv = (w - 2) * 64 + nb * 16 + (l & 15);
        const int rb = mt * 16 + (l >> 4) * 4;
        u32x2 pk; pk.x = pk2bf(acc[0], acc[1]); pk.y = pk2bf(acc[2], acc[3]);
        *(u32x2*)(vtS + nv * 128 + ((rb * 2) ^ ((nv & 7) << 4))) = pk;
      }
    }
  }
  __syncthreads();

  // ---------------- Phase 3: attention via MFMA (swapped S^T trick) ----------------
  // wo frags for phase 4 (issue loads early; L2-hot)
  bf16x8 wof[2][4];
#pragma unroll
  for (int nt = 0; nt < 2; ++nt) {
    const unsigned short* src = wOb + (w * 32 + nt * 16 + (l & 15)) * 128 + (l >> 4) * 8;
#pragma unroll
    for (int ks = 0; ks < 4; ++ks) wof[nt][ks] = *(const bf16x8*)(src + ks * 32);
  }
  {
    const int h  = w >> 1;
    const int qc = l & 7;
    const int g4 = l >> 4;
    const bool valid = ((l >> 5) & 1) == ((l >> 3) & 1);
    float bias[4];
#pragma unroll
    for (int j = 0; j < 4; ++j)
      bias[j] = s_rel[h * 16 + (g4 & 1) * 4 + j - qc + 7];

#pragma unroll
    for (int uu = 0; uu < 2; ++uu) {
      const int T = (w & 1) * 2 + uu;
      const int row = T * 16 + (l & 15);
      const int sw = (row & 7) << 4;
      // S^T = K·Q^T : A = K rows, B = Q rows
      bf16x8 kf = *(const bf16x8*)(qkS + row * 256 + ((128 + h * 64 + g4 * 16) ^ sw));
      bf16x8 qf = *(const bf16x8*)(qkS + row * 256 + ((h * 64 + g4 * 16) ^ sw));
      f32x4 zero = {0.f, 0.f, 0.f, 0.f};
      f32x4 st = __builtin_amdgcn_mfma_f32_16x16x32_bf16(kf, qf, zero, 0, 0, 0);
      // lane: q-row m = l&15, key k = g4*4+j  (valid iff same batch-8 block)
      float s0[4];
#pragma unroll
      for (int j = 0; j < 4; ++j)
        s0[j] = valid ? st[j] * 0.17677669529663687f + bias[j] : -1e30f;
      float mx = fmaxf(fmaxf(s0[0], s0[1]), fmaxf(s0[2], s0[3]));
      mx = fmaxf(mx, __shfl_xor(mx, 16));
      mx = fmaxf(mx, __shfl_xor(mx, 32));
      float p[4], sum = 0.f;
#pragma unroll
      for (int j = 0; j < 4; ++j) { p[j] = __expf(s0[j] - mx); sum += p[j]; }
      sum += __shfl_xor(sum, 16);
      sum += __shfl_xor(sum, 32);
      const float inv = 1.0f / sum;
#pragma unroll
      for (int j = 0; j < 4; ++j) p[j] *= inv;

      if (valid) {
        float* ap = attn_out + ((b0 + (row >> 3)) * 2 + h) * 64 + qc * 8 + (g4 & 1) * 4;
        f32x4 pv = {p[0], p[1], p[2], p[3]};
        *(f32x4*)ap = pv;
      }

      // Build P^T B-fragment (x32, k=0..15 real, 16..31 zero)
      const unsigned P0 = pk2bf(p[0], p[1]);
      const unsigned P1 = pk2bf(p[2], p[3]);
      const int sA = (l & 15) + (g4 & 1) * 32;
      UB8 pf;
      pf.d[0] = (unsigned)__shfl((int)P0, sA);
      pf.d[1] = (unsigned)__shfl((int)P1, sA);
      pf.d[2] = (unsigned)__shfl((int)P0, sA + 16);
      pf.d[3] = (unsigned)__shfl((int)P1, sA + 16);
      if (g4 >= 2) { pf.d[0] = 0; pf.d[1] = 0; pf.d[2] = 0; pf.d[3] = 0; }

      // ctx^T = V^T · P^T : A = Vt rows, B = pf. Output packed b64 into xcA.
#pragma unroll
      for (int vb = 0; vb < 4; ++vb) {
        const int nv = h * 64 + vb * 16 + (l & 15);
        const int kb = (32 * T + 16 * (g4 & 1)) ^ ((nv & 7) << 4);
        bf16x8 vf = *(const bf16x8*)(vtS + nv * 128 + kb);
        f32x4 c = __builtin_amdgcn_mfma_f32_16x16x32_bf16(vf, pf.v, zero, 0, 0, 0);
        // lane: q-row (col) = l&15 -> row; v = vb*16 + g4*4 + j
        u32x2 pk; pk.x = pk2bf(c[0], c[1]); pk.y = pk2bf(c[2], c[3]);
        const int fb = (h * 128 + vb * 32 + g4 * 8) ^ sw;
        *(u32x2*)(xcS + row * 256 + fb) = pk;
      }
    }
  }
  __syncthreads();

  // gamma/beta to regs for phase 5 (L2-hot broadcast)
  const int cg = (t & 15) * 8;
  f32x4 gm0 = *(const f32x4*)(gamma + cg);
  f32x4 gm1 = *(const f32x4*)(gamma + cg + 4);
  f32x4 bt0 = *(const f32x4*)(beta + cg);
  f32x4 bt1 = *(const f32x4*)(beta + cg + 4);

  // ---------------- Phase 4: out = ctx @ Wo^T (A=Wo, B=ctx) -> hbuf f32 swz ----------------
#pragma unroll
  for (int mt = 0; mt < 4; ++mt) {
    bf16x8 cf[4];
    const int row = mt * 16 + (l & 15);
#pragma unroll
    for (int ks = 0; ks < 4; ++ks)
      cf[ks] = *(const bf16x8*)(xcS + row * 256 + ((ks * 64 + (l >> 4) * 16) ^ ((row & 7) << 4)));
#pragma unroll
    for (int nt = 0; nt < 2; ++nt) {
      f32x4 acc = {0.f, 0.f, 0.f, 0.f};
#pragma unroll
      for (int ks = 0; ks < 4; ++ks)
        acc = __builtin_amdgcn_mfma_f32_16x16x32_bf16(wof[nt][ks], cf[ks], acc, 0, 0, 0);
      // lane: out cols n = w*32+nt*16+(l>>4)*4+j for row m -> f32x4
      const int colb = ((w * 32 + nt * 16 + (l >> 4) * 4) * 4) ^ ((row & 7) << 4);
      *(f32x4*)(hbS + row * 512 + colb) = acc;
    }
  }
  __syncthreads();

  // ---------------- Phase 5: residual + LayerNorm + store (reg shuffles, no extra barriers) ----------------
  {
    float* yb = y_out + b0 * 1024;
#pragma unroll
    for (int i = 0; i < 4; ++i) {
      const int g = t + 256 * i;
      const int m = g >> 4;
      const int sw = (m & 7) << 4;
      const char* hp = hbS + m * 512;
      f32x4 h0 = *(const f32x4*)(hp + ((cg * 4) ^ sw));
      f32x4 h1 = *(const f32x4*)(hp + ((cg * 4 + 16) ^ sw));
      float sum = 0.f, sq = 0.f;
#pragma unroll
      for (int j = 0; j < 4; ++j) {
        h0[j] += xr[i][0][j]; h1[j] += xr[i][1][j];
        sum += h0[j] + h1[j];
        sq  += h0[j] * h0[j] + h1[j] * h1[j];
      }
#pragma unroll
      for (int d = 1; d < 16; d <<= 1) {
        sum += __shfl_xor(sum, d);
        sq  += __shfl_xor(sq, d);
      }
      const float mu = sum * 0.0078125f;
      const float rs = rsqrtf(sq * 0.0078125f - mu * mu + 1e-5f);
      f32x4 o0, o1;
#pragma unroll
      for (int j = 0; j < 4; ++j) {
        o0[j] = (h0[j] - mu) * rs * gm0[j] + bt0[j];
        o1[j] = (h1[j] - mu) * rs * gm1[j] + bt1[j];
      }
      *(f32x4*)(yb + g * 8) = o0;
      *(f32x4*)(yb + g * 8 + 4) = o1;
    }
  }
}

extern "C" void kernel_launch(void* const* d_in, const int* in_sizes, int n_in,
                              void* d_out, int out_size, void* d_ws, size_t ws_size,
                              hipStream_t stream) {
  (void)in_sizes; (void)n_in; (void)out_size; (void)ws_size;
  const float* x    = (const float*)d_in[0];
  const float* Wq   = (const float*)d_in[1];
  const float* Wk   = (const float*)d_in[2];
  const float* Wv   = (const float*)d_in[3];
  const float* Wo   = (const float*)d_in[4];
  const float* gam  = (const float*)d_in[5];
  const float* bet  = (const float*)d_in[6];
  const float* relb = (const float*)d_in[7];
  float* y    = (float*)d_out;
  float* attn = y + (size_t)65536 * 1024;
  unsigned short* ws = (unsigned short*)d_ws;

  hipLaunchKernelGGL(wconv_kernel, dim3(192), dim3(256), 0, stream, Wq, Wk, Wv, Wo, ws);
  hipLaunchKernelGGL(wlmha_kernel, dim3(8192), dim3(256), 0, stream,
                     x, ws, ws + 32768, gam, bet, relb, y, attn);
}